// Round 3
// baseline (811.656 us; speedup 1.0000x reference)
//
#include <hip/hip_runtime.h>

typedef unsigned short u16;
typedef __bf16 bf16_t;
typedef bf16_t bf16x8 __attribute__((ext_vector_type(8)));
typedef float f32x4 __attribute__((ext_vector_type(4)));
typedef u16 u16x8 __attribute__((ext_vector_type(8)));

#define AS1 __attribute__((address_space(1)))
#define AS3 __attribute__((address_space(3)))

__device__ __forceinline__ u16 f2bf(float f) {
    union { float f; unsigned u; } v; v.f = f;
    unsigned r = v.u + 0x7FFFu + ((v.u >> 16) & 1u);
    return (u16)(r >> 16);
}
__device__ __forceinline__ float bf2f(u16 s) {
    union { unsigned u; float f; } v; v.u = ((unsigned)s) << 16;
    return v.f;
}

__device__ __forceinline__ void gload_lds16(const u16* g, u16* l) {
    __builtin_amdgcn_global_load_lds((AS1 const void*)g, (AS3 void*)l, 16, 0, 0);
}

// ---------------- big GEMM: C[M,N] = A[M,K] * B[N,K]^T, bf16 in, 128x128 tile ----
// m97 structure + G4 XOR swizzle + T1 bijective XCD-chunked block swizzle (m204).
template <bool OUT_BF16, bool GUARD>
__global__ __launch_bounds__(256) void gemm_bt(
    const u16* __restrict__ A, const u16* __restrict__ B, void* __restrict__ Cv,
    int K, int ldc, int Mreal, int Nreal)
{
    __shared__ u16 As[128 * 64];
    __shared__ u16 Bs[128 * 64];
    const int t = threadIdx.x;
    const int w = t >> 6, l = t & 63;

    const int nwg = gridDim.x * gridDim.y;
    const int lin = blockIdx.y * gridDim.x + blockIdx.x;
    const int xcd = lin & 7, loc = lin >> 3;
    const int q = nwg >> 3, r = nwg & 7;
    const int swz = (xcd < r ? xcd * (q + 1) : r * (q + 1) + (xcd - r) * q) + loc;
    const int bx = swz % gridDim.x, by = swz / gridDim.x;

    const int m0 = by * 128, n0 = bx * 128;
    const int wm = (w >> 1) * 64, wn = (w & 1) * 64;

    const int srow = w << 5;           // wave's 32-row staging base
    const int lrow = l >> 3, lc = l & 7;

    f32x4 acc[4][4] = {};

    for (int kt = 0; kt < K; kt += 64) {
#pragma unroll
        for (int i = 0; i < 4; ++i) {
            int row = srow + i * 8 + lrow;
            int gc = ((lc ^ (row & 7)) << 3);
            const u16* ga = A + (size_t)(m0 + row) * K + kt + gc;
            const u16* gb = B + (size_t)(n0 + row) * K + kt + gc;
            u16* la = &As[(srow + i * 8) * 64];
            u16* lb = &Bs[(srow + i * 8) * 64];
            gload_lds16(ga, la);
            gload_lds16(gb, lb);
        }
        asm volatile("s_waitcnt vmcnt(0)");
        __syncthreads();

#pragma unroll
        for (int kk = 0; kk < 2; ++kk) {
            bf16x8 af[4], bfr[4];
            int kc = kk * 4 + (l >> 4);
#pragma unroll
            for (int mi = 0; mi < 4; ++mi) {
                int row = wm + mi * 16 + (l & 15);
                af[mi] = *(const bf16x8*)&As[row * 64 + ((kc ^ (row & 7)) << 3)];
            }
#pragma unroll
            for (int ni = 0; ni < 4; ++ni) {
                int col = wn + ni * 16 + (l & 15);
                bfr[ni] = *(const bf16x8*)&Bs[col * 64 + ((kc ^ (col & 7)) << 3)];
            }
#pragma unroll
            for (int mi = 0; mi < 4; ++mi)
#pragma unroll
                for (int ni = 0; ni < 4; ++ni)
                    acc[mi][ni] = __builtin_amdgcn_mfma_f32_16x16x32_bf16(
                        af[mi], bfr[ni], acc[mi][ni], 0, 0, 0);
        }
        __syncthreads();
    }

    // epilogue: C/D layout col=lane&15, row=(lane>>4)*4+q  [m89]
#pragma unroll
    for (int mi = 0; mi < 4; ++mi) {
#pragma unroll
        for (int qq = 0; qq < 4; ++qq) {
            int row = m0 + wm + mi * 16 + (l >> 4) * 4 + qq;
            if (GUARD && row >= Mreal) continue;
#pragma unroll
            for (int ni = 0; ni < 4; ++ni) {
                int col = n0 + wn + ni * 16 + (l & 15);
                if (GUARD && col >= Nreal) continue;
                float v = acc[mi][ni][qq];
                if (OUT_BF16) ((u16*)Cv)[(size_t)row * ldc + col] = f2bf(v);
                else          ((float*)Cv)[(size_t)row * ldc + col] = v;
            }
        }
    }
}

// ---------------- fused conv+GEMM1: xs1 = bf16(X) @ W1s^T, sd = X.vd ----------------
// A-tile reg-staged from fp32 X (convert + swizzled ds_write); B via gload_lds.
__global__ __launch_bounds__(256) void gemm_xw(
    const float* __restrict__ X, const u16* __restrict__ B, u16* __restrict__ C,
    const float* __restrict__ vd, float* __restrict__ sd)
{
    __shared__ u16 As[128 * 64];
    __shared__ u16 Bs[128 * 64];
    const int t = threadIdx.x;
    const int w = t >> 6, l = t & 63;

    const int nwg = gridDim.x * gridDim.y;   // (4, 235)
    const int lin = blockIdx.y * gridDim.x + blockIdx.x;
    const int xcd = lin & 7, loc = lin >> 3;
    const int q = nwg >> 3, r = nwg & 7;
    const int swz = (xcd < r ? xcd * (q + 1) : r * (q + 1) + (xcd - r) * q) + loc;
    const int bx = swz % gridDim.x, by = swz / gridDim.x;

    const int m0 = by * 128, n0 = bx * 128;
    const int wm = (w >> 1) * 64, wn = (w & 1) * 64;

    const int srow = w << 5;
    const int lrow = l >> 3, lc = l & 7;

    f32x4 acc[4][4] = {};
    float sdp[4] = {0.f, 0.f, 0.f, 0.f};

    for (int kt = 0; kt < 3072; kt += 64) {
        // B staging: async, pre-swizzled global -> linear LDS
#pragma unroll
        for (int i = 0; i < 4; ++i) {
            int row = srow + i * 8 + lrow;
            int gc = ((lc ^ (row & 7)) << 3);
            gload_lds16(B + (size_t)(n0 + row) * 3072 + kt + gc, &Bs[(srow + i * 8) * 64]);
        }
        // A staging: fp32 load + convert + swizzled ds_write, fused sd partial
        int c = kt + lc * 8;
#pragma unroll
        for (int i = 0; i < 4; ++i) {
            int row = srow + i * 8 + lrow;
            int grow = m0 + row;
            float4 v0 = make_float4(0.f, 0.f, 0.f, 0.f), v1 = v0;
            if (grow < 30000 && c < 3000) {
                const float* p = X + (size_t)grow * 3000 + c;
                v0 = *(const float4*)p;
                v1 = *(const float4*)(p + 4);
                const float* pv = vd + c;
                float4 w0 = *(const float4*)pv;
                float4 w1 = *(const float4*)(pv + 4);
                sdp[i] += v0.x * w0.x + v0.y * w0.y + v0.z * w0.z + v0.w * w0.w
                        + v1.x * w1.x + v1.y * w1.y + v1.z * w1.z + v1.w * w1.w;
            }
            u16x8 o;
            o[0] = f2bf(v0.x); o[1] = f2bf(v0.y); o[2] = f2bf(v0.z); o[3] = f2bf(v0.w);
            o[4] = f2bf(v1.x); o[5] = f2bf(v1.y); o[6] = f2bf(v1.z); o[7] = f2bf(v1.w);
            *(u16x8*)&As[row * 64 + ((lc ^ (row & 7)) << 3)] = o;
        }
        asm volatile("s_waitcnt vmcnt(0)");
        __syncthreads();

#pragma unroll
        for (int kk = 0; kk < 2; ++kk) {
            bf16x8 af[4], bfr[4];
            int kc = kk * 4 + (l >> 4);
#pragma unroll
            for (int mi = 0; mi < 4; ++mi) {
                int row = wm + mi * 16 + (l & 15);
                af[mi] = *(const bf16x8*)&As[row * 64 + ((kc ^ (row & 7)) << 3)];
            }
#pragma unroll
            for (int ni = 0; ni < 4; ++ni) {
                int col = wn + ni * 16 + (l & 15);
                bfr[ni] = *(const bf16x8*)&Bs[col * 64 + ((kc ^ (col & 7)) << 3)];
            }
#pragma unroll
            for (int mi = 0; mi < 4; ++mi)
#pragma unroll
                for (int ni = 0; ni < 4; ++ni)
                    acc[mi][ni] = __builtin_amdgcn_mfma_f32_16x16x32_bf16(
                        af[mi], bfr[ni], acc[mi][ni], 0, 0, 0);
        }
        __syncthreads();
    }

    // sd: one column-block owns the write; reduce over the 8 lanes sharing a row
    if (bx == 0) {
#pragma unroll
        for (int i = 0; i < 4; ++i) {
            float v = sdp[i];
            v += __shfl_xor(v, 1);
            v += __shfl_xor(v, 2);
            v += __shfl_xor(v, 4);
            int grow = m0 + srow + i * 8 + lrow;
            if (lc == 0 && grow < 30000) sd[grow] = v;
        }
    }

#pragma unroll
    for (int mi = 0; mi < 4; ++mi)
#pragma unroll
        for (int qq = 0; qq < 4; ++qq) {
            int row = m0 + wm + mi * 16 + (l >> 4) * 4 + qq;
#pragma unroll
            for (int ni = 0; ni < 4; ++ni) {
                int col = n0 + wn + ni * 16 + (l & 15);
                C[(size_t)row * 512 + col] = f2bf(acc[mi][ni][qq]);
            }
        }
}

// ---------------- v_d[i] = sum_h W1d[h,i]*a1d[h] ----------------
__global__ void k_vd(const float* __restrict__ W1d, const float* __restrict__ a1d,
                     float* __restrict__ vd) {
    int i = blockIdx.x * 256 + threadIdx.x;
    if (i >= 3000) return;
    float acc = 0.f;
    for (int h = 0; h < 512; ++h) acc += W1d[(size_t)h * 3000 + i] * a1d[h];
    vd[i] = acc;
}

// ---------------- W1s -> bf16 [512][3072] (K-pad) ----------------
__global__ void k_w1sb(const float* __restrict__ W1s, u16* __restrict__ wb) {
    int idx = blockIdx.x * 256 + threadIdx.x;
    if (idx >= 512 * 768) return;
    int n = idx / 768, g = idx % 768, k = g * 4;
    ushort4 o = make_ushort4(0, 0, 0, 0);
    if (k < 3000) {
        float4 v = *(const float4*)(W1s + (size_t)n * 3000 + k);
        o.x = f2bf(v.x); o.y = f2bf(v.y); o.z = f2bf(v.z); o.w = f2bf(v.w);
    }
    *(ushort4*)(wb + (size_t)n * 3072 + k) = o;
}

// ---------------- W1s^T -> bf16 [3072][512] (N-pad) ----------------
__global__ void k_w1st(const float* __restrict__ W1s, u16* __restrict__ wt) {
    int idx = blockIdx.x * 256 + threadIdx.x;
    if (idx >= 3072 * 512) return;
    int n = idx >> 9, k = idx & 511;
    wt[idx] = (n < 3000) ? f2bf(W1s[(size_t)k * 3000 + n]) : (u16)0;
}

// ---------------- W2s -> bf16 [128][512] (N-pad) ----------------
__global__ void k_w2b(const float* __restrict__ W2s, u16* __restrict__ wb) {
    int idx = blockIdx.x * 256 + threadIdx.x;
    if (idx >= 128 * 512) return;
    int n = idx >> 9, k = idx & 511;
    wb[idx] = (n < 30) ? f2bf(W2s[(size_t)n * 512 + k]) : (u16)0;
}

// ---------------- ss[n] = xs1b[n,:] . a1s ----------------
__global__ void k_ss(const u16* __restrict__ xs1, const float* __restrict__ a1s,
                     float* __restrict__ ss) {
    int n = blockIdx.x, l = threadIdx.x;
    const u16* row = xs1 + (size_t)n * 512 + l * 8;
    const float* a = a1s + l * 8;
    ushort4 u0 = *(const ushort4*)row;
    ushort4 u1 = *(const ushort4*)(row + 4);
    float4 w0 = *(const float4*)a;
    float4 w1 = *(const float4*)(a + 4);
    float acc = bf2f(u0.x) * w0.x + bf2f(u0.y) * w0.y + bf2f(u0.z) * w0.z + bf2f(u0.w) * w0.w
              + bf2f(u1.x) * w1.x + bf2f(u1.y) * w1.y + bf2f(u1.z) * w1.z + bf2f(u1.w) * w1.w;
#pragma unroll
    for (int s = 32; s; s >>= 1) acc += __shfl_xor(acc, s);
    if (l == 0) ss[n] = acc;
}

// ---------------- CSR build ----------------
__global__ void k_deg(const int* __restrict__ dst, unsigned* __restrict__ deg) {
    int j = blockIdx.x * 256 + threadIdx.x;
    if (j < 180000) atomicAdd(&deg[dst[j]], 1u);
}

// two-level scan: block sums -> scan sums -> per-block offsets (+cur init)
__global__ void k_scan1(const unsigned* __restrict__ deg, unsigned* __restrict__ bsum, int n) {
    __shared__ unsigned ws[4];
    int i = blockIdx.x * 256 + threadIdx.x;
    unsigned v = (i < n) ? deg[i] : 0u;
#pragma unroll
    for (int s = 32; s; s >>= 1) v += __shfl_xor(v, s);
    if ((threadIdx.x & 63) == 0) ws[threadIdx.x >> 6] = v;
    __syncthreads();
    if (threadIdx.x == 0) bsum[blockIdx.x] = ws[0] + ws[1] + ws[2] + ws[3];
}

__global__ void k_scan2(const unsigned* __restrict__ bsum, unsigned* __restrict__ boff,
                        unsigned* __restrict__ off_end, int nb) {
    __shared__ unsigned tmp[128];
    int t = threadIdx.x;
    unsigned v = (t < nb) ? bsum[t] : 0u;
    tmp[t] = v;
    __syncthreads();
    for (int s = 1; s < 128; s <<= 1) {
        unsigned a = (t >= s) ? tmp[t - s] : 0u;
        __syncthreads();
        tmp[t] += a;
        __syncthreads();
    }
    if (t < nb) boff[t] = tmp[t] - v;
    if (t == nb - 1) *off_end = tmp[t];
}

__global__ void k_scan3(const unsigned* __restrict__ deg, const unsigned* __restrict__ boff,
                        unsigned* __restrict__ off, unsigned* __restrict__ cur, int n) {
    __shared__ unsigned tmp[256];
    int b = blockIdx.x, t = threadIdx.x, i = b * 256 + t;
    unsigned v = (i < n) ? deg[i] : 0u;
    tmp[t] = v;
    __syncthreads();
    for (int s = 1; s < 256; s <<= 1) {
        unsigned a = (t >= s) ? tmp[t - s] : 0u;
        __syncthreads();
        tmp[t] += a;
        __syncthreads();
    }
    if (i < n) {
        unsigned o = boff[b] + tmp[t] - v;
        off[i] = o;
        cur[i] = o;
    }
}

__global__ void k_fill(const int* __restrict__ dst, unsigned* __restrict__ cur,
                       unsigned* __restrict__ csr) {
    int j = blockIdx.x * 256 + threadIdx.x;
    if (j >= 180000) return;
    unsigned pos = atomicAdd(&cur[dst[j]], 1u);
    csr[pos] = (unsigned)j;
}

// ---------------- edge scores: e = leaky_relu(ss[src]+sd[dst], 0.2) ----------------
__global__ void k_escore(const int* __restrict__ src, const int* __restrict__ dst,
                         const float* __restrict__ ss, const float* __restrict__ sd,
                         float* __restrict__ e) {
    int j = blockIdx.x * 256 + threadIdx.x;
    if (j >= 180000) return;
    float v = ss[src[j]] + sd[dst[j]];
    e[j] = v > 0.f ? v : 0.2f * v;
}

// ---------------- per-node softmax (in-place e -> alpha) ----------------
__global__ void k_soft(float* __restrict__ ea, const unsigned* __restrict__ csr,
                       const unsigned* __restrict__ off) {
    int n = blockIdx.x, l = threadIdx.x;
    unsigned lo = off[n], hi = off[n + 1];
    if (lo == hi) return;
    float m = -1e30f;
    for (unsigned i = lo + l; i < hi; i += 64) m = fmaxf(m, ea[csr[i]]);
#pragma unroll
    for (int s = 32; s; s >>= 1) m = fmaxf(m, __shfl_xor(m, s));
    float den = 0.f;
    for (unsigned i = lo + l; i < hi; i += 64) den += expf(ea[csr[i]] - m);
#pragma unroll
    for (int s = 32; s; s >>= 1) den += __shfl_xor(den, s);
    float inv = 1.f / den;
    for (unsigned i = lo + l; i < hi; i += 64) {
        unsigned j = csr[i];
        ea[j] = expf(ea[j] - m) * inv;
    }
}

// ---------------- aggregation + ELU: out[n] = elu(sum alpha_e * xin[src_e]) ------
__global__ void k_agg(const u16* __restrict__ xin, const float* __restrict__ alpha,
                      const unsigned* __restrict__ csr, const unsigned* __restrict__ off,
                      const int* __restrict__ src, u16* __restrict__ outb, int nvalid) {
    __shared__ int   lsrc[256];
    __shared__ float lalp[256];
    int n = blockIdx.x, t = threadIdx.x;
    float a0 = 0.f, a1 = 0.f;
    if (n < nvalid) {
        unsigned lo = off[n], hi = off[n + 1];
        for (unsigned base = lo; base < hi; base += 256) {
            int cnt = (int)min(256u, hi - base);
            if (t < cnt) {
                unsigned j = csr[base + t];
                lsrc[t] = src[j];
                lalp[t] = alpha[j];
            }
            __syncthreads();
            for (int i = 0; i < cnt; ++i) {
                const u16* row = xin + (size_t)lsrc[i] * 512;
                float wgt = lalp[i];
                a0 += wgt * bf2f(row[t]);
                a1 += wgt * bf2f(row[t + 256]);
            }
            __syncthreads();
        }
    }
    a0 = a0 > 0.f ? a0 : expf(a0) - 1.f;
    a1 = a1 > 0.f ? a1 : expf(a1) - 1.f;
    size_t o = (size_t)n * 512 + t;
    outb[o] = f2bf(a0);
    outb[o + 256] = f2bf(a1);
}

// ---------------- xs3[n,h] = h2[n,:] . W2s[:,h]  (K=30) -> bf16 ----------------
__global__ void k_xs3(const float* __restrict__ h2, const float* __restrict__ W2s,
                      u16* __restrict__ xs3) {
    int t = threadIdx.x;
    size_t n0 = (size_t)blockIdx.x * 8;
    float w0[30], w1[30];
#pragma unroll
    for (int o = 0; o < 30; ++o) {
        w0[o] = W2s[(size_t)o * 512 + t];
        w1[o] = W2s[(size_t)o * 512 + t + 256];
    }
    for (int r = 0; r < 8; ++r) {
        size_t n = n0 + r;
        const float* hr = h2 + n * 30;
        float a0 = 0.f, a1 = 0.f;
#pragma unroll
        for (int o = 0; o < 30; ++o) {
            float v = hr[o];
            a0 += v * w0[o];
            a1 += v * w1[o];
        }
        xs3[n * 512 + t] = f2bf(a0);
        xs3[n * 512 + t + 256] = f2bf(a1);
    }
}

extern "C" void kernel_launch(void* const* d_in, const int* in_sizes, int n_in,
                              void* d_out, int out_size, void* d_ws, size_t ws_size,
                              hipStream_t stream) {
    const float* X   = (const float*)d_in[0];
    const int*   ei  = (const int*)d_in[1];
    const float* W1s = (const float*)d_in[2];
    const float* W1d = (const float*)d_in[3];
    const float* a1s = (const float*)d_in[4];
    const float* a1d = (const float*)d_in[5];
    const float* W2s = (const float*)d_in[6];
    const int* src = ei;
    const int* dst = ei + 180000;

    float* out = (float*)d_out;
    float* h2 = out;               // [30000][30]
    float* h4 = out + 900000;      // [30000][3000]

    // scratch inside d_out h4 region (dead before gemm5 overwrites it)
    char* ob = (char*)(out + 900000);
    u16* xs1b = (u16*)ob;                                  // 30080*512
    u16* h1b  = (u16*)(ob + 30801920);                     // 30080*512
    u16* xs3b = (u16*)(ob + 30801920 + 30801920);          // 30000*512

    // ws scratch (must survive gemm5): h3b + W1sT + small vectors
    char* w = (char*)d_ws;
    auto carve = [&](size_t bytes) { char* p = w; w += (bytes + 255) & ~(size_t)255; return p; };
    u16* w1sb = (u16*)carve((size_t)512 * 3072 * 2);
    u16* w1st = (u16*)carve((size_t)3072 * 512 * 2);
    u16* w2sb = (u16*)carve((size_t)128 * 512 * 2);
    u16* h3b  = (u16*)carve((size_t)30080 * 512 * 2);
    float* vd    = (float*)carve(3000 * 4);
    float* ss    = (float*)carve(30000 * 4);
    float* sd    = (float*)carve(30000 * 4);
    float* alpha = (float*)carve(180000 * 4);
    unsigned* deg = (unsigned*)carve(30000 * 4);
    unsigned* off = (unsigned*)carve(30004 * 4);
    unsigned* cur = (unsigned*)carve(30000 * 4);
    unsigned* csr = (unsigned*)carve(180000 * 4);
    unsigned* bsum = (unsigned*)carve(128 * 4);
    unsigned* boff = (unsigned*)carve(128 * 4);

    hipMemsetAsync(deg, 0, 30000 * 4, stream);

    k_vd  <<<12, 256, 0, stream>>>(W1d, a1d, vd);
    k_w1sb<<<1536, 256, 0, stream>>>(W1s, w1sb);
    k_w1st<<<6144, 256, 0, stream>>>(W1s, w1st);
    k_w2b <<<256, 256, 0, stream>>>(W2s, w2sb);

    // fused: xs1 = bf16(X) @ W1s^T  +  sd = X.vd  (replaces convX + gemm1)
    gemm_xw<<<dim3(4, 235), 256, 0, stream>>>(X, w1sb, xs1b, vd, sd);

    k_ss  <<<30000, 64, 0, stream>>>(xs1b, a1s, ss);
    k_deg <<<704, 256, 0, stream>>>(dst, deg);
    k_scan1<<<118, 256, 0, stream>>>(deg, bsum, 30000);
    k_scan2<<<1, 128, 0, stream>>>(bsum, boff, &off[30000], 118);
    k_scan3<<<118, 256, 0, stream>>>(deg, boff, off, cur, 30000);
    k_fill<<<704, 256, 0, stream>>>(dst, cur, csr);
    k_escore<<<704, 256, 0, stream>>>(src, dst, ss, sd, alpha);
    k_soft<<<30000, 64, 0, stream>>>(alpha, csr, off);

    k_agg <<<30080, 256, 0, stream>>>(xs1b, alpha, csr, off, src, h1b, 30000);

    // h2 = h1 @ W2s.T via MFMA
    gemm_bt<false, true><<<dim3(1, 235), 256, 0, stream>>>(h1b, w2sb, h2, 512, 30, 30000, 30);

    k_xs3 <<<3750, 256, 0, stream>>>(h2, W2s, xs3b);
    k_agg <<<30080, 256, 0, stream>>>(xs3b, alpha, csr, off, src, h3b, 30000);

    gemm_bt<false, true><<<dim3(24, 235), 256, 0, stream>>>(h3b, w1st, h4, 512, 3000, 30000, 3000);
}

// Round 4
// 711.540 us; speedup vs baseline: 1.1407x; 1.1407x over previous
//
#include <hip/hip_runtime.h>

typedef unsigned short u16;
typedef __bf16 bf16_t;
typedef bf16_t bf16x8 __attribute__((ext_vector_type(8)));
typedef float f32x4 __attribute__((ext_vector_type(4)));
typedef u16 u16x8 __attribute__((ext_vector_type(8)));

#define AS1 __attribute__((address_space(1)))
#define AS3 __attribute__((address_space(3)))

__device__ __forceinline__ u16 f2bf(float f) {
    union { float f; unsigned u; } v; v.f = f;
    unsigned r = v.u + 0x7FFFu + ((v.u >> 16) & 1u);
    return (u16)(r >> 16);
}
__device__ __forceinline__ float bf2f(u16 s) {
    union { unsigned u; float f; } v; v.u = ((unsigned)s) << 16;
    return v.f;
}

__device__ __forceinline__ void gload_lds16(const u16* g, u16* l) {
    __builtin_amdgcn_global_load_lds((AS1 const void*)g, (AS3 void*)l, 16, 0, 0);
}

// ---------------- big GEMM: C[M,N] = A[M,K] * B[N,K]^T, bf16 in, 128x128 tile ----
// m97 structure + G4 XOR swizzle + T1 bijective XCD-chunked block swizzle (m204).
template <bool OUT_BF16, bool GUARD>
__global__ __launch_bounds__(256) void gemm_bt(
    const u16* __restrict__ A, const u16* __restrict__ B, void* __restrict__ Cv,
    int K, int ldc, int Mreal, int Nreal)
{
    __shared__ u16 As[128 * 64];
    __shared__ u16 Bs[128 * 64];
    const int t = threadIdx.x;
    const int w = t >> 6, l = t & 63;

    const int nwg = gridDim.x * gridDim.y;
    const int lin = blockIdx.y * gridDim.x + blockIdx.x;
    const int xcd = lin & 7, loc = lin >> 3;
    const int q = nwg >> 3, r = nwg & 7;
    const int swz = (xcd < r ? xcd * (q + 1) : r * (q + 1) + (xcd - r) * q) + loc;
    const int bx = swz % gridDim.x, by = swz / gridDim.x;

    const int m0 = by * 128, n0 = bx * 128;
    const int wm = (w >> 1) * 64, wn = (w & 1) * 64;

    const int srow = w << 5;           // wave's 32-row staging base
    const int lrow = l >> 3, lc = l & 7;

    f32x4 acc[4][4] = {};

    for (int kt = 0; kt < K; kt += 64) {
#pragma unroll
        for (int i = 0; i < 4; ++i) {
            int row = srow + i * 8 + lrow;
            int gc = ((lc ^ (row & 7)) << 3);
            const u16* ga = A + (size_t)(m0 + row) * K + kt + gc;
            const u16* gb = B + (size_t)(n0 + row) * K + kt + gc;
            u16* la = &As[(srow + i * 8) * 64];
            u16* lb = &Bs[(srow + i * 8) * 64];
            gload_lds16(ga, la);
            gload_lds16(gb, lb);
        }
        asm volatile("s_waitcnt vmcnt(0)");
        __syncthreads();

#pragma unroll
        for (int kk = 0; kk < 2; ++kk) {
            bf16x8 af[4], bfr[4];
            int kc = kk * 4 + (l >> 4);
#pragma unroll
            for (int mi = 0; mi < 4; ++mi) {
                int row = wm + mi * 16 + (l & 15);
                af[mi] = *(const bf16x8*)&As[row * 64 + ((kc ^ (row & 7)) << 3)];
            }
#pragma unroll
            for (int ni = 0; ni < 4; ++ni) {
                int col = wn + ni * 16 + (l & 15);
                bfr[ni] = *(const bf16x8*)&Bs[col * 64 + ((kc ^ (col & 7)) << 3)];
            }
#pragma unroll
            for (int mi = 0; mi < 4; ++mi)
#pragma unroll
                for (int ni = 0; ni < 4; ++ni)
                    acc[mi][ni] = __builtin_amdgcn_mfma_f32_16x16x32_bf16(
                        af[mi], bfr[ni], acc[mi][ni], 0, 0, 0);
        }
        __syncthreads();
    }

    // epilogue: C/D layout col=lane&15, row=(lane>>4)*4+q  [m89]
#pragma unroll
    for (int mi = 0; mi < 4; ++mi) {
#pragma unroll
        for (int qq = 0; qq < 4; ++qq) {
            int row = m0 + wm + mi * 16 + (l >> 4) * 4 + qq;
            if (GUARD && row >= Mreal) continue;
#pragma unroll
            for (int ni = 0; ni < 4; ++ni) {
                int col = n0 + wn + ni * 16 + (l & 15);
                if (GUARD && col >= Nreal) continue;
                float v = acc[mi][ni][qq];
                if (OUT_BF16) ((u16*)Cv)[(size_t)row * ldc + col] = f2bf(v);
                else          ((float*)Cv)[(size_t)row * ldc + col] = v;
            }
        }
    }
}

// ---------------- v_d[i] = sum_h W1d[h,i]*a1d[h] ----------------
__global__ void k_vd(const float* __restrict__ W1d, const float* __restrict__ a1d,
                     float* __restrict__ vd) {
    int i = blockIdx.x * 256 + threadIdx.x;
    if (i >= 3000) return;
    float acc = 0.f;
    for (int h = 0; h < 512; ++h) acc += W1d[(size_t)h * 3000 + i] * a1d[h];
    vd[i] = acc;
}

// ---------------- W1s -> bf16 [512][3072] (K-pad) ----------------
__global__ void k_w1sb(const float* __restrict__ W1s, u16* __restrict__ wb) {
    int idx = blockIdx.x * 256 + threadIdx.x;
    if (idx >= 512 * 768) return;
    int n = idx / 768, g = idx % 768, k = g * 4;
    ushort4 o = make_ushort4(0, 0, 0, 0);
    if (k < 3000) {
        float4 v = *(const float4*)(W1s + (size_t)n * 3000 + k);
        o.x = f2bf(v.x); o.y = f2bf(v.y); o.z = f2bf(v.z); o.w = f2bf(v.w);
    }
    *(ushort4*)(wb + (size_t)n * 3072 + k) = o;
}

// ---------------- W1s^T -> bf16 [3072][512] (N-pad) ----------------
__global__ void k_w1st(const float* __restrict__ W1s, u16* __restrict__ wt) {
    int idx = blockIdx.x * 256 + threadIdx.x;
    if (idx >= 3072 * 512) return;
    int n = idx >> 9, k = idx & 511;
    wt[idx] = (n < 3000) ? f2bf(W1s[(size_t)k * 3000 + n]) : (u16)0;
}

// ---------------- W2s -> bf16 [128][512] (N-pad) ----------------
__global__ void k_w2b(const float* __restrict__ W2s, u16* __restrict__ wb) {
    int idx = blockIdx.x * 256 + threadIdx.x;
    if (idx >= 128 * 512) return;
    int n = idx >> 9, k = idx & 511;
    wb[idx] = (n < 30) ? f2bf(W2s[(size_t)n * 512 + k]) : (u16)0;
}

// ---------------- X fp32 -> bf16 padded [30080][3072], fused sd = X.vd ----------
__global__ void k_convX(const float* __restrict__ X, u16* __restrict__ xb,
                        const float* __restrict__ vd, float* __restrict__ sd) {
    __shared__ float red[4];
    int n = blockIdx.x, t = threadIdx.x;
    u16* brow = xb + (size_t)n * 3072;
    if (n < 30000) {
        const float* xrow = X + (size_t)n * 3000;
        float part = 0.f;
#pragma unroll
        for (int it = 0; it < 3; ++it) {
            int c = (t + it * 256) * 4;
            ushort4 o = make_ushort4(0, 0, 0, 0);
            if (c < 3000) {
                float4 v = *(const float4*)(xrow + c);
                float4 wv = *(const float4*)(vd + c);
                o.x = f2bf(v.x); o.y = f2bf(v.y); o.z = f2bf(v.z); o.w = f2bf(v.w);
                part += v.x * wv.x + v.y * wv.y + v.z * wv.z + v.w * wv.w;
            }
            *(ushort4*)(brow + c) = o;
        }
#pragma unroll
        for (int s = 32; s; s >>= 1) part += __shfl_xor(part, s);
        if ((t & 63) == 0) red[t >> 6] = part;
        __syncthreads();
        if (t == 0) sd[n] = red[0] + red[1] + red[2] + red[3];
    } else {
#pragma unroll
        for (int it = 0; it < 3; ++it)
            *(ushort4*)(brow + (t + it * 256) * 4) = make_ushort4(0, 0, 0, 0);
    }
}

// ---------------- ss[n] = xs1b[n,:] . a1s  (4 nodes/block, wave each) ----------
__global__ void k_ss(const u16* __restrict__ xs1, const float* __restrict__ a1s,
                     float* __restrict__ ss) {
    int w = threadIdx.x >> 6, l = threadIdx.x & 63;
    int n = blockIdx.x * 4 + w;
    if (n >= 30000) return;
    const u16* row = xs1 + (size_t)n * 512 + l * 8;
    const float* a = a1s + l * 8;
    ushort4 u0 = *(const ushort4*)row;
    ushort4 u1 = *(const ushort4*)(row + 4);
    float4 w0 = *(const float4*)a;
    float4 w1 = *(const float4*)(a + 4);
    float acc = bf2f(u0.x) * w0.x + bf2f(u0.y) * w0.y + bf2f(u0.z) * w0.z + bf2f(u0.w) * w0.w
              + bf2f(u1.x) * w1.x + bf2f(u1.y) * w1.y + bf2f(u1.z) * w1.z + bf2f(u1.w) * w1.w;
#pragma unroll
    for (int s = 32; s; s >>= 1) acc += __shfl_xor(acc, s);
    if (l == 0) ss[n] = acc;
}

// ---------------- CSR build ----------------
__global__ void k_deg(const int* __restrict__ dst, unsigned* __restrict__ deg) {
    int j = blockIdx.x * 256 + threadIdx.x;
    if (j < 180000) atomicAdd(&deg[dst[j]], 1u);
}

__global__ void k_scan1(const unsigned* __restrict__ deg, unsigned* __restrict__ bsum, int n) {
    __shared__ unsigned ws[4];
    int i = blockIdx.x * 256 + threadIdx.x;
    unsigned v = (i < n) ? deg[i] : 0u;
#pragma unroll
    for (int s = 32; s; s >>= 1) v += __shfl_xor(v, s);
    if ((threadIdx.x & 63) == 0) ws[threadIdx.x >> 6] = v;
    __syncthreads();
    if (threadIdx.x == 0) bsum[blockIdx.x] = ws[0] + ws[1] + ws[2] + ws[3];
}

__global__ void k_scan2(const unsigned* __restrict__ bsum, unsigned* __restrict__ boff,
                        unsigned* __restrict__ off_end, int nb) {
    __shared__ unsigned tmp[128];
    int t = threadIdx.x;
    unsigned v = (t < nb) ? bsum[t] : 0u;
    tmp[t] = v;
    __syncthreads();
    for (int s = 1; s < 128; s <<= 1) {
        unsigned a = (t >= s) ? tmp[t - s] : 0u;
        __syncthreads();
        tmp[t] += a;
        __syncthreads();
    }
    if (t < nb) boff[t] = tmp[t] - v;
    if (t == nb - 1) *off_end = tmp[t];
}

__global__ void k_scan3(const unsigned* __restrict__ deg, const unsigned* __restrict__ boff,
                        unsigned* __restrict__ off, unsigned* __restrict__ cur, int n) {
    __shared__ unsigned tmp[256];
    int b = blockIdx.x, t = threadIdx.x, i = b * 256 + t;
    unsigned v = (i < n) ? deg[i] : 0u;
    tmp[t] = v;
    __syncthreads();
    for (int s = 1; s < 256; s <<= 1) {
        unsigned a = (t >= s) ? tmp[t - s] : 0u;
        __syncthreads();
        tmp[t] += a;
        __syncthreads();
    }
    if (i < n) {
        unsigned o = boff[b] + tmp[t] - v;
        off[i] = o;
        cur[i] = o;
    }
}

__global__ void k_fill(const int* __restrict__ dst, unsigned* __restrict__ cur,
                       unsigned* __restrict__ csr) {
    int j = blockIdx.x * 256 + threadIdx.x;
    if (j >= 180000) return;
    unsigned pos = atomicAdd(&cur[dst[j]], 1u);
    csr[pos] = (unsigned)j;
}

// ---------------- fused score+softmax: alpha from ss/sd, 8-lane groups ----------
__global__ void k_soft(const int* __restrict__ src, const float* __restrict__ ss,
                       const float* __restrict__ sd, float* __restrict__ alpha,
                       const unsigned* __restrict__ csr, const unsigned* __restrict__ off) {
    int t = threadIdx.x;
    int g = t >> 3, l = t & 7;
    int n = blockIdx.x * 32 + g;
    if (n >= 30000) return;
    unsigned lo = off[n], hi = off[n + 1];
    if (lo == hi) return;
    float sdn = sd[n];
    float m = -1e30f;
    for (unsigned i = lo + l; i < hi; i += 8) {
        float v = ss[src[csr[i]]] + sdn;
        v = v > 0.f ? v : 0.2f * v;
        m = fmaxf(m, v);
    }
    m = fmaxf(m, __shfl_xor(m, 1));
    m = fmaxf(m, __shfl_xor(m, 2));
    m = fmaxf(m, __shfl_xor(m, 4));
    float den = 0.f;
    for (unsigned i = lo + l; i < hi; i += 8) {
        float v = ss[src[csr[i]]] + sdn;
        v = v > 0.f ? v : 0.2f * v;
        den += expf(v - m);
    }
    den += __shfl_xor(den, 1);
    den += __shfl_xor(den, 2);
    den += __shfl_xor(den, 4);
    float inv = 1.f / den;
    for (unsigned i = lo + l; i < hi; i += 8) {
        unsigned j = csr[i];
        float v = ss[src[j]] + sdn;
        v = v > 0.f ? v : 0.2f * v;
        alpha[j] = expf(v - m) * inv;
    }
}

// ---------------- aggregation + ELU: wave per node, bf16x8 loads ----------------
__global__ void k_agg(const u16* __restrict__ xin, const float* __restrict__ alpha,
                      const unsigned* __restrict__ csr, const unsigned* __restrict__ off,
                      const int* __restrict__ src, u16* __restrict__ outb, int nvalid) {
    int w = threadIdx.x >> 6, l = threadIdx.x & 63;
    int n = blockIdx.x * 4 + w;
    float acc[8] = {};
    if (n < nvalid) {
        unsigned lo = off[n], hi = off[n + 1];
        for (unsigned i = lo; i < hi; ++i) {
            unsigned j = csr[i];
            float av = alpha[j];
            int sj = src[j];
            u16x8 row = *(const u16x8*)&xin[(size_t)sj * 512 + l * 8];
#pragma unroll
            for (int k = 0; k < 8; ++k) acc[k] += av * bf2f(row[k]);
        }
    }
    u16x8 o;
#pragma unroll
    for (int k = 0; k < 8; ++k) {
        float a = acc[k] > 0.f ? acc[k] : expf(acc[k]) - 1.f;
        o[k] = f2bf(a);
    }
    *(u16x8*)&outb[(size_t)n * 512 + l * 8] = o;
}

// ---------------- xs3[n,h] = h2[n,:] . W2s[:,h]  (K=30) -> bf16 ----------------
__global__ void k_xs3(const float* __restrict__ h2, const float* __restrict__ W2s,
                      u16* __restrict__ xs3) {
    int t = threadIdx.x;
    size_t n0 = (size_t)blockIdx.x * 8;
    float w0[30], w1[30];
#pragma unroll
    for (int o = 0; o < 30; ++o) {
        w0[o] = W2s[(size_t)o * 512 + t];
        w1[o] = W2s[(size_t)o * 512 + t + 256];
    }
    for (int r = 0; r < 8; ++r) {
        size_t n = n0 + r;
        const float* hr = h2 + n * 30;
        float a0 = 0.f, a1 = 0.f;
#pragma unroll
        for (int o = 0; o < 30; ++o) {
            float v = hr[o];
            a0 += v * w0[o];
            a1 += v * w1[o];
        }
        xs3[n * 512 + t] = f2bf(a0);
        xs3[n * 512 + t + 256] = f2bf(a1);
    }
}

extern "C" void kernel_launch(void* const* d_in, const int* in_sizes, int n_in,
                              void* d_out, int out_size, void* d_ws, size_t ws_size,
                              hipStream_t stream) {
    const float* X   = (const float*)d_in[0];
    const int*   ei  = (const int*)d_in[1];
    const float* W1s = (const float*)d_in[2];
    const float* W1d = (const float*)d_in[3];
    const float* a1s = (const float*)d_in[4];
    const float* a1d = (const float*)d_in[5];
    const float* W2s = (const float*)d_in[6];
    const int* src = ei;
    const int* dst = ei + 180000;

    float* out = (float*)d_out;
    float* h2 = out;               // [30000][30]
    float* h4 = out + 900000;      // [30000][3000]

    // scratch inside d_out h4 region (dead before gemm5 overwrites it)
    char* ob = (char*)(out + 900000);
    u16* xbf  = (u16*)ob;                                        // 30080*3072 bf16
    u16* xs1b = (u16*)(ob + 184811520);                          // 30080*512
    u16* h1b  = (u16*)(ob + 184811520 + 30801920);               // 30080*512
    u16* xs3b = (u16*)(ob + 184811520 + 30801920 + 30801920);    // 30080*512

    // ws scratch (must survive gemm5): h3b + W1sT + small vectors
    char* w = (char*)d_ws;
    auto carve = [&](size_t bytes) { char* p = w; w += (bytes + 255) & ~(size_t)255; return p; };
    u16* w1sb = (u16*)carve((size_t)512 * 3072 * 2);
    u16* w1st = (u16*)carve((size_t)3072 * 512 * 2);
    u16* w2sb = (u16*)carve((size_t)128 * 512 * 2);
    u16* h3b  = (u16*)carve((size_t)30080 * 512 * 2);
    float* vd    = (float*)carve(3000 * 4);
    float* ss    = (float*)carve(30000 * 4);
    float* sd    = (float*)carve(30000 * 4);
    float* alpha = (float*)carve(180000 * 4);
    unsigned* deg = (unsigned*)carve(30000 * 4);
    unsigned* off = (unsigned*)carve(30004 * 4);
    unsigned* cur = (unsigned*)carve(30000 * 4);
    unsigned* csr = (unsigned*)carve(180000 * 4);
    unsigned* bsum = (unsigned*)carve(128 * 4);
    unsigned* boff = (unsigned*)carve(128 * 4);

    hipMemsetAsync(deg, 0, 30000 * 4, stream);

    k_vd  <<<12, 256, 0, stream>>>(W1d, a1d, vd);
    k_w1sb<<<1536, 256, 0, stream>>>(W1s, w1sb);
    k_w1st<<<6144, 256, 0, stream>>>(W1s, w1st);
    k_w2b <<<256, 256, 0, stream>>>(W2s, w2sb);
    k_convX<<<30080, 256, 0, stream>>>(X, xbf, vd, sd);

    gemm_bt<true, false><<<dim3(4, 235), 256, 0, stream>>>(xbf, w1sb, xs1b, 3072, 512, 0, 0);

    k_ss  <<<7500, 256, 0, stream>>>(xs1b, a1s, ss);
    k_deg <<<704, 256, 0, stream>>>(dst, deg);
    k_scan1<<<118, 256, 0, stream>>>(deg, bsum, 30000);
    k_scan2<<<1, 128, 0, stream>>>(bsum, boff, &off[30000], 118);
    k_scan3<<<118, 256, 0, stream>>>(deg, boff, off, cur, 30000);
    k_fill<<<704, 256, 0, stream>>>(dst, cur, csr);
    k_soft<<<938, 256, 0, stream>>>(src, ss, sd, alpha, csr, off);

    k_agg <<<7520, 256, 0, stream>>>(xs1b, alpha, csr, off, src, h1b, 30000);

    // h2 = h1 @ W2s.T via MFMA
    gemm_bt<false, true><<<dim3(1, 235), 256, 0, stream>>>(h1b, w2sb, h2, 512, 30, 30000, 30);

    k_xs3 <<<3750, 256, 0, stream>>>(h2, W2s, xs3b);
    k_agg <<<7520, 256, 0, stream>>>(xs3b, alpha, csr, off, src, h3b, 30000);

    gemm_bt<false, true><<<dim3(24, 235), 256, 0, stream>>>(h3b, w1st, h4, 512, 3000, 30000, 3000);
}